// Round 8
// baseline (377.910 us; speedup 1.0000x reference)
//
#include <hip/hip_runtime.h>
#include <math.h>

#define NROWS 4096
#define KCODES 8192
#define DDIM 512
#define IDX_OFF 2097152    // NROWS*DDIM
#define L0_OFF  2101248
#define L1_OFF  2101249
#define ENT_OFF 2101250
#define ARGMAX_MARGIN 0.05f
#define FIX_CHUNK 256
#define FIX_CPR (KCODES / FIX_CHUNK)   // 32 chunks per flagged row

#define TOP2_UPD(v1, k1, v2, k2, h, k)                                 \
    do {                                                               \
        if ((h) > (v1)) { v2 = v1; k2 = k1; v1 = (h); k1 = (k); }      \
        else if ((h) > (v2)) { v2 = (h); k2 = (k); }                   \
    } while (0)

typedef __attribute__((ext_vector_type(8))) short bf16x8;
typedef __attribute__((ext_vector_type(4))) float f32x4;

// fast gumbel: hardware log (v_log_f32), error ~1e-5 absolute -- covered by
// the 0.05 fixup margin and negligible vs bf16 P storage.
__device__ __forceinline__ float gumbelfast(float u) {
    float a = __logf(u + 1e-10f);
    float b = __logf(1e-10f - a);
    return -b;
}
__device__ __forceinline__ ushort f2bf(float f) {
    uint u = __float_as_uint(f);
    return (ushort)((u + 0x7FFFu + ((u >> 16) & 1u)) >> 16);
}
__device__ __forceinline__ float bf2f(ushort h) {
    return __uint_as_float(((uint)h) << 16);
}

// ---- numpy-faithful fp32 helpers ----
__device__ __forceinline__ float np_log32(float x) {
    return (float)log((double)x);
}
__device__ __forceinline__ float np_gumbel(float u) {
    float a  = __fadd_rn(u, 1e-10f);
    float la = np_log32(a);
    float b  = __fadd_rn(-la, 1e-10f);
    float lb = np_log32(b);
    return -lb;
}
__device__ float np_sumsq512(const float* __restrict__ a) {
    float blk[4];
    #pragma unroll
    for (int b = 0; b < 4; ++b) {
        const float* p = a + b * 128;
        float r[8];
        #pragma unroll
        for (int j = 0; j < 8; ++j) r[j] = __fmul_rn(p[j], p[j]);
        for (int i = 8; i < 128; i += 8) {
            #pragma unroll
            for (int j = 0; j < 8; ++j)
                r[j] = __fadd_rn(r[j], __fmul_rn(p[i + j], p[i + j]));
        }
        blk[b] = __fadd_rn(__fadd_rn(__fadd_rn(r[0], r[1]), __fadd_rn(r[2], r[3])),
                           __fadd_rn(__fadd_rn(r[4], r[5]), __fadd_rn(r[6], r[7])));
    }
    return __fadd_rn(__fadd_rn(blk[0], blk[1]), __fadd_rn(blk[2], blk[3]));
}

__device__ __forceinline__ float dot4(float4 a, float4 b) {
    return a.x*b.x + a.y*b.y + a.z*b.z + a.w*b.w;
}
__device__ __forceinline__ void fma4(float4& o, float p, float4 c) {
    o.x += p*c.x; o.y += p*c.y; o.z += p*c.z; o.w += p*c.w;
}

// ================= shared small kernels =================
__global__ __launch_bounds__(256) void vq_csq(const float* __restrict__ cb,
                                              float* __restrict__ csq,
                                              int* __restrict__ flag_cnt) {
    if (blockIdx.x == 0 && threadIdx.x == 0) flag_cnt[0] = 0;
    int row = blockIdx.x * 256 + threadIdx.x;
    if (row < KCODES) csq[row] = np_sumsq512(cb + (size_t)row * DDIM);
}

// ---------------- R3-proven serial fixup (fallback path only) ----------------
__global__ __launch_bounds__(256) void vq_fixup(
        const float* __restrict__ x, const float* __restrict__ cb,
        const float* __restrict__ u2, const float* __restrict__ csq,
        const int* __restrict__ flag_cnt, const int* __restrict__ flag_rows,
        float* __restrict__ out) {
    __shared__ float xrow[DDIM];
    __shared__ float bv[4];
    __shared__ int   bk[4];
    const int n = flag_cnt[0];
    for (int w = blockIdx.x; w < n; w += gridDim.x) {
        const int row = flag_rows[w];
        for (int i = threadIdx.x; i < DDIM; i += 256)
            xrow[i] = x[(size_t)row * DDIM + i];
        __syncthreads();
        const float xsq = np_sumsq512(xrow);
        float best = -1e30f; int bidx = 0x7fffffff;
        for (int k = threadIdx.x; k < KCODES; k += 256) {
            const float* c = cb + (size_t)k * DDIM;
            float acc1 = 0.f, acc2 = 0.f;
            #pragma unroll 8
            for (int d = 0; d < 384; ++d) acc1 = fmaf(xrow[d], c[d], acc1);
            #pragma unroll 8
            for (int d = 384; d < DDIM; ++d) acc2 = fmaf(xrow[d], c[d], acc2);
            float xc = __fadd_rn(acc1, acc2);
            float t1 = __fadd_rn(xsq, csq[k]);
            float t2 = __fmul_rn(2.0f, xc);
            float t3 = __fsub_rn(t1, t2);
            float logit = -t3;
            float h = __fadd_rn(logit, np_gumbel(u2[(size_t)row * KCODES + k]));
            if (h > best || (h == best && k < bidx)) { best = h; bidx = k; }
        }
        const int lane = threadIdx.x & 63, wv = threadIdx.x >> 6;
        #pragma unroll
        for (int m = 32; m >= 1; m >>= 1) {
            float ov = __shfl_xor(best, m); int ok = __shfl_xor(bidx, m);
            if (ov > best || (ov == best && ok < bidx)) { best = ov; bidx = ok; }
        }
        if (lane == 0) { bv[wv] = best; bk[wv] = bidx; }
        __syncthreads();
        if (threadIdx.x == 0) {
            float b = bv[0]; int bi = bk[0];
            #pragma unroll
            for (int i = 1; i < 4; ++i)
                if (bv[i] > b || (bv[i] == b && bk[i] < bi)) { b = bv[i]; bi = bk[i]; }
            out[IDX_OFF + row] = (float)bi;
        }
        __syncthreads();
    }
}

// ---------------- parallel fixup: (row x chunk) work items, packed atomicMax ----------------
__global__ __launch_bounds__(256) void vq_fixup2(
        const float* __restrict__ x, const float* __restrict__ cb,
        const float* __restrict__ u2, const float* __restrict__ csq,
        const int* __restrict__ flag_cnt, const int* __restrict__ flag_rows,
        unsigned long long* __restrict__ packed) {
    __shared__ float xrow[DDIM];
    __shared__ float xsq_sh;
    __shared__ unsigned long long redp[4];
    const int n = flag_cnt[0];
    const int total = n * FIX_CPR;
    for (int item = blockIdx.x; item < total; item += gridDim.x) {
        const int w = item / FIX_CPR;
        const int chunk = item - w * FIX_CPR;
        const int row = flag_rows[w];
        __syncthreads();                       // protect xrow across loop iters
        for (int i = threadIdx.x; i < DDIM; i += 256)
            xrow[i] = x[(size_t)row * DDIM + i];
        __syncthreads();
        if (threadIdx.x == 0) xsq_sh = np_sumsq512(xrow);
        __syncthreads();
        const float xsq = xsq_sh;
        const int k = chunk * FIX_CHUNK + threadIdx.x;
        const float* c = cb + (size_t)k * DDIM;
        float acc1 = 0.f, acc2 = 0.f;
        #pragma unroll 8
        for (int d = 0; d < 384; ++d) acc1 = fmaf(xrow[d], c[d], acc1);
        #pragma unroll 8
        for (int d = 384; d < DDIM; ++d) acc2 = fmaf(xrow[d], c[d], acc2);
        float xc = __fadd_rn(acc1, acc2);
        float t1 = __fadd_rn(xsq, csq[k]);
        float t2 = __fmul_rn(2.0f, xc);
        float logit = -__fsub_rn(t1, t2);
        float h = __fadd_rn(logit, np_gumbel(u2[(size_t)row * KCODES + k]));
        uint hb = __float_as_uint(h);
        uint key = (hb & 0x80000000u) ? ~hb : (hb | 0x80000000u);
        unsigned long long val = ((unsigned long long)key << 32)
                               | (unsigned long long)(0xFFFFFFFFu - (uint)k);
        #pragma unroll
        for (int m = 32; m >= 1; m >>= 1) {
            unsigned long long o = __shfl_xor(val, m);
            if (o > val) val = o;
        }
        if ((threadIdx.x & 63) == 0) redp[threadIdx.x >> 6] = val;
        __syncthreads();
        if (threadIdx.x == 0) {
            unsigned long long v = redp[0];
            if (redp[1] > v) v = redp[1];
            if (redp[2] > v) v = redp[2];
            if (redp[3] > v) v = redp[3];
            atomicMax(&packed[row], v);
        }
    }
}

// ================= FAST PATH =================

// split fp32 -> bf16 hi/lo
__global__ __launch_bounds__(256) void vq_split(const float4* __restrict__ in,
                                                ushort* __restrict__ hi,
                                                ushort* __restrict__ lo) {
    int i = blockIdx.x * 256 + threadIdx.x;
    float4 v = in[i];
    ushort4 h, l;
    h.x = f2bf(v.x); h.y = f2bf(v.y); h.z = f2bf(v.z); h.w = f2bf(v.w);
    l.x = f2bf(v.x - bf2f(h.x)); l.y = f2bf(v.y - bf2f(h.y));
    l.z = f2bf(v.z - bf2f(h.z)); l.w = f2bf(v.w - bf2f(h.w));
    ((ushort4*)hi)[i] = h;
    ((ushort4*)lo)[i] = l;
}

// cbT[d][k] = bf16(cb[k][d])
__global__ __launch_bounds__(256) void vq_trans(const float* __restrict__ cb,
                                                ushort* __restrict__ cbT) {
    __shared__ ushort T[64][65];
    const int k0 = blockIdx.x * 64, d0 = blockIdx.y * 64;
    const int lane = threadIdx.x & 63, w = threadIdx.x >> 6;
    #pragma unroll
    for (int i = 0; i < 16; ++i) {
        int ky = i * 4 + w;
        float f = cb[(size_t)(k0 + ky) * DDIM + d0 + lane];
        T[lane][ky] = f2bf(f);
    }
    __syncthreads();
    #pragma unroll
    for (int i = 0; i < 16; ++i) {
        int dy = i * 4 + w;
        cbT[(size_t)(d0 + dy) * KCODES + k0 + lane] = T[dy][lane];
    }
}

// GEMM1: S0[m][n] = 2*(x.cb^T) - csq[n], split-bf16 3-product MFMA
__global__ __launch_bounds__(256) void vq_gemm1(
        const ushort* __restrict__ xhi, const ushort* __restrict__ xlo,
        const ushort* __restrict__ chi, const ushort* __restrict__ clo,
        const float* __restrict__ csq, float* __restrict__ S0) {
    __shared__ short As[2][128 * 72];
    __shared__ short Bs[2][128 * 72];
    const int tid = threadIdx.x;
    const int lane = tid & 63, wid = tid >> 6;
    const int wr = wid >> 1, wc = wid & 1;
    const int m0 = blockIdx.y * 128, n0 = blockIdx.x * 128;

    f32x4 acc[4][4] = {};
    for (int kk = 0; kk < 8; ++kk) {
        const int k0 = kk * 64;
        __syncthreads();
        #pragma unroll
        for (int i = 0; i < 4; ++i) {
            int c = tid + i * 256;
            int row = c >> 3, off = (c & 7) * 8;
            int lidx = row * 72 + off;
            size_t gA = (size_t)(m0 + row) * DDIM + k0 + off;
            size_t gB = (size_t)(n0 + row) * DDIM + k0 + off;
            *(bf16x8*)&As[0][lidx] = *(const bf16x8*)(xhi + gA);
            *(bf16x8*)&As[1][lidx] = *(const bf16x8*)(xlo + gA);
            *(bf16x8*)&Bs[0][lidx] = *(const bf16x8*)(chi + gB);
            *(bf16x8*)&Bs[1][lidx] = *(const bf16x8*)(clo + gB);
        }
        __syncthreads();
        #pragma unroll
        for (int ks = 0; ks < 2; ++ks) {
            const int ko = ks * 32 + (lane >> 4) * 8;
            bf16x8 ah[4], al[4], bh[4], bl[4];
            #pragma unroll
            for (int m = 0; m < 4; ++m) {
                int r = wr * 64 + m * 16 + (lane & 15);
                ah[m] = *(bf16x8*)&As[0][r * 72 + ko];
                al[m] = *(bf16x8*)&As[1][r * 72 + ko];
            }
            #pragma unroll
            for (int n = 0; n < 4; ++n) {
                int r = wc * 64 + n * 16 + (lane & 15);
                bh[n] = *(bf16x8*)&Bs[0][r * 72 + ko];
                bl[n] = *(bf16x8*)&Bs[1][r * 72 + ko];
            }
            #pragma unroll
            for (int m = 0; m < 4; ++m)
                #pragma unroll
                for (int n = 0; n < 4; ++n) {
                    acc[m][n] = __builtin_amdgcn_mfma_f32_16x16x32_bf16(ah[m], bh[n], acc[m][n], 0, 0, 0);
                    acc[m][n] = __builtin_amdgcn_mfma_f32_16x16x32_bf16(ah[m], bl[n], acc[m][n], 0, 0, 0);
                    acc[m][n] = __builtin_amdgcn_mfma_f32_16x16x32_bf16(al[m], bh[n], acc[m][n], 0, 0, 0);
                }
        }
    }
    #pragma unroll
    for (int n = 0; n < 4; ++n) {
        int col = n0 + wc * 64 + n * 16 + (lane & 15);
        float cq = csq[col];
        #pragma unroll
        for (int m = 0; m < 4; ++m) {
            int rbase = m0 + wr * 64 + m * 16 + ((lane >> 4) << 2);
            #pragma unroll
            for (int j = 0; j < 4; ++j)
                S0[(size_t)(rbase + j) * KCODES + col] = 2.0f * acc[m][n][j] - cq;
        }
    }
}

// row softmax / gumbel / argmax v3: 1024-thread blocks (16 waves), all 6
// float4 loads issued up-front per thread (MLP=6), 8 elements/thread.
// Writes P (bf16) in-place over S0 rows.
__global__ __launch_bounds__(1024) void vq_soft(
        float* __restrict__ S0, const float* __restrict__ u1,
        const float* __restrict__ u2,
        float* __restrict__ Aarr, float* __restrict__ entarr,
        float* __restrict__ out, int* __restrict__ flag_cnt,
        int* __restrict__ flag_rows, unsigned long long* __restrict__ packed) {
    __shared__ float redm[16], redA[16], redB[16];
    __shared__ float rv1[16], rv2[16];
    __shared__ int   rk1[16], rk2[16];
    const int row = blockIdx.x, tid = threadIdx.x;
    const int lane = tid & 63, wid = tid >> 6;
    const size_t base = (size_t)row * KCODES;
    if (tid == 0) packed[row] = 0ULL;

    const int ka = tid * 4;            // 0..4092
    const int kb = 4096 + tid * 4;     // 4096..8188
    // issue all 6 loads before any dependent compute
    float4 Sa = *(const float4*)(S0 + base + ka);
    float4 Sb = *(const float4*)(S0 + base + kb);
    float4 Ua = *(const float4*)(u1 + base + ka);
    float4 Ub = *(const float4*)(u1 + base + kb);
    float4 Va = *(const float4*)(u2 + base + ka);
    float4 Vb = *(const float4*)(u2 + base + kb);

    // argmax candidates (h = S + g(u2))
    float v1 = -1e30f, v2 = -1e30f; int k1 = 0x7fffffff, k2 = 0x7fffffff;
    float h;
    h = Sa.x + gumbelfast(Va.x); TOP2_UPD(v1, k1, v2, k2, h, ka);
    h = Sa.y + gumbelfast(Va.y); TOP2_UPD(v1, k1, v2, k2, h, ka + 1);
    h = Sa.z + gumbelfast(Va.z); TOP2_UPD(v1, k1, v2, k2, h, ka + 2);
    h = Sa.w + gumbelfast(Va.w); TOP2_UPD(v1, k1, v2, k2, h, ka + 3);
    h = Sb.x + gumbelfast(Vb.x); TOP2_UPD(v1, k1, v2, k2, h, kb);
    h = Sb.y + gumbelfast(Vb.y); TOP2_UPD(v1, k1, v2, k2, h, kb + 1);
    h = Sb.z + gumbelfast(Vb.z); TOP2_UPD(v1, k1, v2, k2, h, kb + 2);
    h = Sb.w + gumbelfast(Vb.w); TOP2_UPD(v1, k1, v2, k2, h, kb + 3);

    // soft scores s = (S + g(u1)) / 2
    float4 sa, sb;
    sa.x = (Sa.x + gumbelfast(Ua.x)) * 0.5f;
    sa.y = (Sa.y + gumbelfast(Ua.y)) * 0.5f;
    sa.z = (Sa.z + gumbelfast(Ua.z)) * 0.5f;
    sa.w = (Sa.w + gumbelfast(Ua.w)) * 0.5f;
    sb.x = (Sb.x + gumbelfast(Ub.x)) * 0.5f;
    sb.y = (Sb.y + gumbelfast(Ub.y)) * 0.5f;
    sb.z = (Sb.z + gumbelfast(Ub.z)) * 0.5f;
    sb.w = (Sb.w + gumbelfast(Ub.w)) * 0.5f;
    float mloc = fmaxf(fmaxf(fmaxf(sa.x, sa.y), fmaxf(sa.z, sa.w)),
                       fmaxf(fmaxf(sb.x, sb.y), fmaxf(sb.z, sb.w)));
    #pragma unroll
    for (int m = 32; m >= 1; m >>= 1) mloc = fmaxf(mloc, __shfl_xor(mloc, m));
    if (lane == 0) redm[wid] = mloc;
    __syncthreads();
    float mrow = redm[0];
    #pragma unroll
    for (int i = 1; i < 16; ++i) mrow = fmaxf(mrow, redm[i]);

    // exp, accumulate, pack P
    float A, Be;
    {
        float d0 = sa.x - mrow, d1 = sa.y - mrow, d2 = sa.z - mrow, d3 = sa.w - mrow;
        float e0 = __expf(d0), e1 = __expf(d1), e2 = __expf(d2), e3 = __expf(d3);
        float d4 = sb.x - mrow, d5 = sb.y - mrow, d6 = sb.z - mrow, d7 = sb.w - mrow;
        float e4 = __expf(d4), e5 = __expf(d5), e6 = __expf(d6), e7 = __expf(d7);
        A  = (((e0 + e1) + e2) + e3) + ((((e4 + e5) + e6) + e7));
        Be = (((e0*d0 + e1*d1) + e2*d2) + e3*d3) + ((((e4*d4 + e5*d5) + e6*d6) + e7*d7));
        ushort* Prow = (ushort*)(S0 + base);
        ushort4 pa, pb;
        pa.x = f2bf(e0); pa.y = f2bf(e1); pa.z = f2bf(e2); pa.w = f2bf(e3);
        pb.x = f2bf(e4); pb.y = f2bf(e5); pb.z = f2bf(e6); pb.w = f2bf(e7);
        *(ushort4*)(Prow + ka) = pa;
        *(ushort4*)(Prow + kb) = pb;
    }
    #pragma unroll
    for (int m = 32; m >= 1; m >>= 1) { A += __shfl_xor(A, m); Be += __shfl_xor(Be, m); }
    #pragma unroll
    for (int m = 32; m >= 1; m >>= 1) {
        float ov1 = __shfl_xor(v1, m); int ok1 = __shfl_xor(k1, m);
        float ov2 = __shfl_xor(v2, m); int ok2 = __shfl_xor(k2, m);
        if (ov1 > v1 || (ov1 == v1 && ok1 < k1)) {
            float nv2; int nk2;
            if (v1 > ov2 || (v1 == ov2 && k1 < ok2)) { nv2 = v1; nk2 = k1; }
            else { nv2 = ov2; nk2 = ok2; }
            v1 = ov1; k1 = ok1; v2 = nv2; k2 = nk2;
        } else if (ov1 > v2 || (ov1 == v2 && ok1 < k2)) { v2 = ov1; k2 = ok1; }
    }
    if (lane == 0) {
        redA[wid] = A; redB[wid] = Be;
        rv1[wid] = v1; rv2[wid] = v2; rk1[wid] = k1; rk2[wid] = k2;
    }
    __syncthreads();
    if (tid == 0) {
        float At = 0.f, Bt = 0.f;
        #pragma unroll
        for (int i = 0; i < 16; ++i) { At += redA[i]; Bt += redB[i]; }
        float V1 = rv1[0], V2 = rv2[0]; int K1 = rk1[0], K2 = rk2[0];
        #pragma unroll
        for (int i = 1; i < 16; ++i) {
            float ov1 = rv1[i], ov2 = rv2[i]; int ok1 = rk1[i], ok2 = rk2[i];
            if (ov1 > V1 || (ov1 == V1 && ok1 < K1)) {
                float nv2; int nk2;
                if (V1 > ov2 || (V1 == ov2 && K1 < ok2)) { nv2 = V1; nk2 = K1; }
                else { nv2 = ov2; nk2 = ok2; }
                V1 = ov1; K1 = ok1; V2 = nv2; K2 = nk2;
            } else if (ov1 > V2 || (ov1 == V2 && ok1 < K2)) { V2 = ov1; K2 = ok1; }
        }
        Aarr[row] = At;
        entarr[row] = logf(At) - Bt / At;
        out[IDX_OFF + row] = (float)K1;
        if (V1 - V2 < ARGMAX_MARGIN) {
            int s = atomicAdd(flag_cnt, 1);
            flag_rows[s] = row;
        }
    }
}

// GEMM2 v2: 512 threads, 8 waves (4 row x 2 col), BK=128, reg-staged double
// buffer, XCD-friendly flat grid.
#define G2_BK 128
__global__ __launch_bounds__(512) void vq_gemm2b(
        const ushort* __restrict__ P, const ushort* __restrict__ cbT,
        const float* __restrict__ Aarr, const float* __restrict__ x,
        float* __restrict__ out, float* __restrict__ wloss) {
    __shared__ short Ap[2][128 * 136];
    __shared__ short Bt[2][64 * 136];
    __shared__ float redl[8];
    const int tid = threadIdx.x;
    const int lane = tid & 63, wid = tid >> 6;
    const int wr = wid & 3, wc = wid >> 2;
    const int bid = blockIdx.x;
    const int mblk = bid & 31, nblk = bid >> 5;
    const int m0 = mblk * 128, n0 = nblk * 64;

    bf16x8 rp[4], rb[2];
    f32x4 acc[2][2] = {};

    #define G2_LOAD(t)                                                         \
        do {                                                                   \
            const int k0_ = (t) * G2_BK;                                       \
            _Pragma("unroll")                                                  \
            for (int i = 0; i < 4; ++i) {                                      \
                int c = tid + i * 512;                                         \
                int row = c >> 4, off = (c & 15) * 8;                          \
                rp[i] = *(const bf16x8*)(P + (size_t)(m0 + row) * 16384 + k0_ + off); \
            }                                                                  \
            _Pragma("unroll")                                                  \
            for (int i = 0; i < 2; ++i) {                                      \
                int c = tid + i * 512;                                         \
                int row = c >> 4, off = (c & 15) * 8;                          \
                rb[i] = *(const bf16x8*)(cbT + (size_t)(n0 + row) * 8192 + k0_ + off); \
            }                                                                  \
        } while (0)

    #define G2_WRITE(buf)                                                      \
        do {                                                                   \
            _Pragma("unroll")                                                  \
            for (int i = 0; i < 4; ++i) {                                      \
                int c = tid + i * 512;                                         \
                int row = c >> 4, off = (c & 15) * 8;                          \
                *(bf16x8*)&Ap[buf][row * 136 + off] = rp[i];                   \
            }                                                                  \
            _Pragma("unroll")                                                  \
            for (int i = 0; i < 2; ++i) {                                      \
                int c = tid + i * 512;                                         \
                int row = c >> 4, off = (c & 15) * 8;                          \
                *(bf16x8*)&Bt[buf][row * 136 + off] = rb[i];                   \
            }                                                                  \
        } while (0)

    G2_LOAD(0);
    G2_WRITE(0);
    __syncthreads();
    int cur = 0;
    for (int t = 0; t < KCODES / G2_BK; ++t) {
        if (t < KCODES / G2_BK - 1) G2_LOAD(t + 1);
        #pragma unroll
        for (int ks = 0; ks < 4; ++ks) {
            const int ko = ks * 32 + (lane >> 4) * 8;
            bf16x8 af[2], bfr[2];
            #pragma unroll
            for (int m = 0; m < 2; ++m)
                af[m] = *(bf16x8*)&Ap[cur][(wr * 32 + m * 16 + (lane & 15)) * 136 + ko];
            #pragma unroll
            for (int n = 0; n < 2; ++n)
                bfr[n] = *(bf16x8*)&Bt[cur][(wc * 32 + n * 16 + (lane & 15)) * 136 + ko];
            #pragma unroll
            for (int m = 0; m < 2; ++m)
                #pragma unroll
                for (int n = 0; n < 2; ++n)
                    acc[m][n] = __builtin_amdgcn_mfma_f32_16x16x32_bf16(af[m], bfr[n], acc[m][n], 0, 0, 0);
        }
        if (t < KCODES / G2_BK - 1) {
            __syncthreads();
            G2_WRITE(cur ^ 1);
            __syncthreads();
            cur ^= 1;
        }
    }
    #undef G2_LOAD
    #undef G2_WRITE

    float lsum = 0.f;
    #pragma unroll
    for (int n = 0; n < 2; ++n) {
        int col = n0 + wc * 32 + n * 16 + (lane & 15);
        #pragma unroll
        for (int m = 0; m < 2; ++m) {
            int rbase = m0 + wr * 32 + m * 16 + ((lane >> 4) << 2);
            #pragma unroll
            for (int j = 0; j < 4; ++j) {
                int row = rbase + j;
                float inva = 1.0f / Aarr[row];
                float q = acc[m][n][j] * inva;
                out[(size_t)row * DDIM + col] = q;
                float d = q - x[(size_t)row * DDIM + col];
                lsum += d * d;
            }
        }
    }
    #pragma unroll
    for (int m = 32; m >= 1; m >>= 1) lsum += __shfl_xor(lsum, m);
    if (lane == 0) redl[wid] = lsum;
    __syncthreads();
    if (tid == 0) {
        float s = 0.f;
        #pragma unroll
        for (int i = 0; i < 8; ++i) s += redl[i];
        wloss[bid] = s;
    }
}

__global__ __launch_bounds__(256) void vq_finalize2(
        const float* __restrict__ wloss, const float* __restrict__ entarr,
        const int* __restrict__ flag_cnt, const int* __restrict__ flag_rows,
        const unsigned long long* __restrict__ packed, float* __restrict__ out) {
    __shared__ float redl[4], rede[4];
    int tid = threadIdx.x;
    const int n = flag_cnt[0];
    for (int w = tid; w < n; w += 256) {
        int row = flag_rows[w];
        uint lowbits = (uint)(packed[row] & 0xFFFFFFFFULL);
        out[IDX_OFF + row] = (float)(0xFFFFFFFFu - lowbits);
    }
    float l = wloss[tid];
    float e = 0.f;
    #pragma unroll
    for (int i = 0; i < 16; ++i) e += entarr[tid + i * 256];
    #pragma unroll
    for (int m = 32; m >= 1; m >>= 1) { l += __shfl_xor(l, m); e += __shfl_xor(e, m); }
    if ((tid & 63) == 0) { redl[tid >> 6] = l; rede[tid >> 6] = e; }
    __syncthreads();
    if (tid == 0) {
        float L = (((redl[0] + redl[1]) + redl[2]) + redl[3]) * (1.0f / 2097152.0f);
        float E = (((rede[0] + rede[1]) + rede[2]) + rede[3]) * (1.0f / 4096.0f);
        out[L0_OFF]  = L;
        out[L1_OFF]  = L;
        out[ENT_OFF] = E;
    }
}

// ================= FALLBACK PATH (R3-proven fused kernel) =================
#define BR 16
#define KT 128
#define NUM_KT 64
#define NUM_DC 4

__device__ __forceinline__ float gumbelf(float u) {
    return -logf(-logf(u + 1e-10f) + 1e-10f);
}

__global__ __launch_bounds__(256) void vq_main_fb(
        const float* __restrict__ x, const float* __restrict__ cb,
        const float* __restrict__ u1, const float* __restrict__ u2,
        const float* __restrict__ csq, float* __restrict__ out,
        float* __restrict__ wloss, float* __restrict__ went,
        int* __restrict__ flag_cnt, int* __restrict__ flag_rows) {
    __shared__ float4 Xs[BR][129];
    __shared__ float4 Cs[KT * 32];
    __shared__ float4 Ol[BR][128];
    __shared__ float4 Ps[BR][32];
    __shared__ float  xsq_s[BR];
    __shared__ float  f_s[BR];
    __shared__ float  A_s[BR];
    __shared__ float  ent_s[BR];
    __shared__ float  red4[4];

    const int tid = threadIdx.x;
    const int rg  = tid >> 5;
    const int cg  = tid & 31;
    const int r0  = rg * 2;
    const int r1  = r0 + 1;
    const int row0g = blockIdx.x * BR;
    const float4* cb4 = (const float4*)cb;

    {
        const float4* xg = (const float4*)x + (size_t)row0g * 128;
        #pragma unroll
        for (int i = 0; i < 8; ++i) {
            int idx = tid + i * 256;
            int r = idx >> 7, q = idx & 127;
            Xs[r][q] = xg[r * 128 + q];
            Ol[r][q] = make_float4(0.f, 0.f, 0.f, 0.f);
        }
    }
    __syncthreads();
    {
        int r = tid >> 4, part = tid & 15;
        float s = 0.f;
        #pragma unroll
        for (int q = 0; q < 8; ++q) {
            float4 v = Xs[r][part * 8 + q];
            s += v.x*v.x + v.y*v.y + v.z*v.z + v.w*v.w;
        }
        #pragma unroll
        for (int m = 8; m >= 1; m >>= 1) s += __shfl_xor(s, m);
        if (part == 0) xsq_s[r] = s;
    }
    __syncthreads();
    const float xsq0 = xsq_s[r0];
    const float xsq1 = xsq_s[r1];

    float m0 = -1e30f, m1 = -1e30f;
    float A0 = 0.f, A1 = 0.f;
    float B0 = 0.f, B1 = 0.f;
    float hb0 = -1e30f, hb1 = -1e30f;
    float hc0 = -1e30f, hc1 = -1e30f;
    int   kb0 = 0, kb1 = 0, kc0 = 0, kc1 = 0;

    for (int t = 0; t < NUM_KT; ++t) {
        const int ktb = t * KT;
        float a00=0.f,a01=0.f,a02=0.f,a03=0.f,a10=0.f,a11=0.f,a12=0.f,a13=0.f;

        for (int dc = 0; dc < NUM_DC; ++dc) {
            #pragma unroll
            for (int i = 0; i < 16; ++i) {
                int idx = tid + i * 256;
                int k = idx >> 5, q = idx & 31;
                Cs[k * 32 + (q ^ ((k >> 2) & 7))] =
                    cb4[(size_t)(ktb + k) * 128 + dc * 32 + q];
            }
            __syncthreads();
            const int qb = dc * 32;
            const int c4 = cg * 4;
            #pragma unroll 4
            for (int dd = 0; dd < 32; ++dd) {
                float4 xv0 = Xs[r0][qb + dd];
                float4 xv1 = Xs[r1][qb + dd];
                int swq = dd ^ (cg & 7);
                float4 cv0 = Cs[(c4 + 0) * 32 + swq];
                float4 cv1 = Cs[(c4 + 1) * 32 + swq];
                float4 cv2 = Cs[(c4 + 2) * 32 + swq];
                float4 cv3 = Cs[(c4 + 3) * 32 + swq];
                a00 += dot4(xv0, cv0); a01 += dot4(xv0, cv1);
                a02 += dot4(xv0, cv2); a03 += dot4(xv0, cv3);
                a10 += dot4(xv1, cv0); a11 += dot4(xv1, cv1);
                a12 += dot4(xv1, cv2); a13 += dot4(xv1, cv3);
            }
            __syncthreads();
        }
        {
            const int kg0 = ktb + cg * 4;
            size_t ur0 = (size_t)(row0g + r0) * KCODES + kg0;
            size_t ur1 = (size_t)(row0g + r1) * KCODES + kg0;
            float4 u1a = *(const float4*)(u1 + ur0);
            float4 u1b = *(const float4*)(u1 + ur1);
            float4 u2a = *(const float4*)(u2 + ur0);
            float4 u2b = *(const float4*)(u2 + ur1);
            float cs0 = csq[kg0], cs1 = csq[kg0+1], cs2 = csq[kg0+2], cs3 = csq[kg0+3];
            {
                float l0 = 2.f*a00 - xsq0 - cs0;
                float l1 = 2.f*a01 - xsq0 - cs1;
                float l2 = 2.f*a02 - xsq0 - cs2;
                float l3 = 2.f*a03 - xsq0 - cs3;
                float h;
                h = l0 + gumbelf(u2a.x); TOP2_UPD(hb0, kb0, hc0, kc0, h, kg0);
                h = l1 + gumbelf(u2a.y); TOP2_UPD(hb0, kb0, hc0, kc0, h, kg0+1);
                h = l2 + gumbelf(u2a.z); TOP2_UPD(hb0, kb0, hc0, kc0, h, kg0+2);
                h = l3 + gumbelf(u2a.w); TOP2_UPD(hb0, kb0, hc0, kc0, h, kg0+3);
                float s0 = (l0 + gumbelf(u1a.x)) * 0.5f;
                float s1 = (l1 + gumbelf(u1a.y)) * 0.5f;
                float s2 = (l2 + gumbelf(u1a.z)) * 0.5f;
                float s3 = (l3 + gumbelf(u1a.w)) * 0.5f;
                float tmax = fmaxf(fmaxf(s0, s1), fmaxf(s2, s3));
                #pragma unroll
                for (int m = 16; m >= 1; m >>= 1) tmax = fmaxf(tmax, __shfl_xor(tmax, m));
                float mn = fmaxf(m0, tmax);
                float p0 = expf(s0 - mn), p1 = expf(s1 - mn);
                float p2 = expf(s2 - mn), p3 = expf(s3 - mn);
                float tA = p0 + p1 + p2 + p3;
                float tB = p0*(s0-mn) + p1*(s1-mn) + p2*(s2-mn) + p3*(s3-mn);
                #pragma unroll
                for (int m = 16; m >= 1; m >>= 1) { tA += __shfl_xor(tA, m); tB += __shfl_xor(tB, m); }
                float f = expf(m0 - mn);
                B0 = f * (B0 + (m0 - mn) * A0) + tB;
                A0 = f * A0 + tA;
                m0 = mn;
                Ps[r0][cg] = make_float4(p0, p1, p2, p3);
                if (cg == 0) f_s[r0] = f;
            }
            {
                float l0 = 2.f*a10 - xsq1 - cs0;
                float l1 = 2.f*a11 - xsq1 - cs1;
                float l2 = 2.f*a12 - xsq1 - cs2;
                float l3 = 2.f*a13 - xsq1 - cs3;
                float h;
                h = l0 + gumbelf(u2b.x); TOP2_UPD(hb1, kb1, hc1, kc1, h, kg0);
                h = l1 + gumbelf(u2b.y); TOP2_UPD(hb1, kb1, hc1, kc1, h, kg0+1);
                h = l2 + gumbelf(u2b.z); TOP2_UPD(hb1, kb1, hc1, kc1, h, kg0+2);
                h = l3 + gumbelf(u2b.w); TOP2_UPD(hb1, kb1, hc1, kc1, h, kg0+3);
                float s0 = (l0 + gumbelf(u1b.x)) * 0.5f;
                float s1 = (l1 + gumbelf(u1b.y)) * 0.5f;
                float s2 = (l2 + gumbelf(u1b.z)) * 0.5f;
                float s3 = (l3 + gumbelf(u1b.w)) * 0.5f;
                float tmax = fmaxf(fmaxf(s0, s1), fmaxf(s2, s3));
                #pragma unroll
                for (int m = 16; m >= 1; m >>= 1) tmax = fmaxf(tmax, __shfl_xor(tmax, m));
                float mn = fmaxf(m1, tmax);
                float p0 = expf(s0 - mn), p1 = expf(s1 - mn);
                float p2 = expf(s2 - mn), p3 = expf(s3 - mn);
                float tA = p0 + p1 + p2 + p3;
                float tB = p0*(s0-mn) + p1*(s1-mn) + p2*(s2-mn) + p3*(s3-mn);
                #pragma unroll
                for (int m = 16; m >= 1; m >>= 1) { tA += __shfl_xor(tA, m); tB += __shfl_xor(tB, m); }
                float f = expf(m1 - mn);
                B1 = f * (B1 + (m1 - mn) * A1) + tB;
                A1 = f * A1 + tA;
                m1 = mn;
                Ps[r1][cg] = make_float4(p0, p1, p2, p3);
                if (cg == 0) f_s[r1] = f;
            }
        }
        __syncthreads();

        for (int dc = 0; dc < NUM_DC; ++dc) {
            #pragma unroll
            for (int i = 0; i < 16; ++i) {
                int idx = tid + i * 256;
                int k = idx >> 5, q = idx & 31;
                Cs[k * 32 + (q ^ ((k >> 2) & 7))] =
                    cb4[(size_t)(ktb + k) * 128 + dc * 32 + q];
            }
            __syncthreads();
            float4 o0 = make_float4(0.f,0.f,0.f,0.f);
            float4 o1 = make_float4(0.f,0.f,0.f,0.f);
            #pragma unroll 2
            for (int k4 = 0; k4 < 32; ++k4) {
                float4 pv0 = Ps[r0][k4];
                float4 pv1 = Ps[r1][k4];
                int sq = cg ^ (k4 & 7);
                float4 cva = Cs[(k4*4 + 0) * 32 + sq];
                float4 cvb = Cs[(k4*4 + 1) * 32 + sq];
                float4 cvc = Cs[(k4*4 + 2) * 32 + sq];
                float4 cvd = Cs[(k4*4 + 3) * 32 + sq];
                fma4(o0, pv0.x, cva); fma4(o0, pv0.y, cvb);
                fma4(o0, pv0.z, cvc); fma4(o0, pv0.w, cvd);
                fma4(o1, pv1.x, cva); fma4(o1, pv1.y, cvb);
                fma4(o1, pv1.z, cvc); fma4(o1, pv1.w, cvd);
            }
            float fr0 = f_s[r0], fr1 = f_s[r1];
            int oq = dc * 32 + cg;
            float4 Ov0 = Ol[r0][oq];
            Ov0.x = Ov0.x*fr0 + o0.x; Ov0.y = Ov0.y*fr0 + o0.y;
            Ov0.z = Ov0.z*fr0 + o0.z; Ov0.w = Ov0.w*fr0 + o0.w;
            Ol[r0][oq] = Ov0;
            float4 Ov1 = Ol[r1][oq];
            Ov1.x = Ov1.x*fr1 + o1.x; Ov1.y = Ov1.y*fr1 + o1.y;
            Ov1.z = Ov1.z*fr1 + o1.z; Ov1.w = Ov1.w*fr1 + o1.w;
            Ol[r1][oq] = Ov1;
            __syncthreads();
        }
    }
    {
        float ent0 = logf(A0) - B0 / A0;
        float v1 = hb0, v2 = hc0; int k1 = kb0, k2 = kc0;
        #pragma unroll
        for (int m = 16; m >= 1; m >>= 1) {
            float ov1 = __shfl_xor(v1, m); int ok1 = __shfl_xor(k1, m);
            float ov2 = __shfl_xor(v2, m); int ok2 = __shfl_xor(k2, m);
            if (ov1 > v1 || (ov1 == v1 && ok1 < k1)) {
                float nv2; int nk2;
                if (v1 > ov2 || (v1 == ov2 && k1 < ok2)) { nv2 = v1; nk2 = k1; }
                else { nv2 = ov2; nk2 = ok2; }
                v1 = ov1; k1 = ok1; v2 = nv2; k2 = nk2;
            } else if (ov1 > v2 || (ov1 == v2 && ok1 < k2)) {
                v2 = ov1; k2 = ok1;
            }
        }
        if (cg == 0) {
            out[IDX_OFF + row0g + r0] = (float)k1;
            if (v1 - v2 < ARGMAX_MARGIN) {
                int s = atomicAdd(flag_cnt, 1);
                flag_rows[s] = row0g + r0;
            }
            ent_s[r0] = ent0;
            A_s[r0] = A0;
        }
        float ent1 = logf(A1) - B1 / A1;
        v1 = hb1; v2 = hc1; k1 = kb1; k2 = kc1;
        #pragma unroll
        for (int m = 16; m >= 1; m >>= 1) {
            float ov1 = __shfl_xor(v1, m); int ok1 = __shfl_xor(k1, m);
            float ov2 = __shfl_xor(v2, m); int ok2 = __shfl_xor(k2, m);
            if (ov1 > v1 || (ov1 == v1 && ok1 < k1)) {
                float nv2; int nk2;
                if (v1 > ov2 || (v1 == ov2 && k1 < ok2)) { nv2 = v1; nk2 = k1; }
                else { nv2 = ov2; nk2 = ok2; }
                v1 = ov1; k1 = ok1; v2 = nv2; k2 = nk2;
            } else if (ov1 > v2 || (ov1 == v2 && ok1 < k2)) {
                v2 = ov1; k2 = ok1;
            }
        }
        if (cg == 0) {
            out[IDX_OFF + row0g + r1] = (float)k1;
            if (v1 - v2 < ARGMAX_MARGIN) {
                int s = atomicAdd(flag_cnt, 1);
                flag_rows[s] = row0g + r1;
            }
            ent_s[r1] = ent1;
            A_s[r1] = A1;
        }
    }
    __syncthreads();

    float lsum = 0.f;
    float4* outq = (float4*)out;
    #pragma unroll
    for (int i = 0; i < 8; ++i) {
        int idx = tid + i * 256;
        int r = idx >> 7, q = idx & 127;
        float inva = 1.f / A_s[r];
        float4 Ov = Ol[r][q];
        float4 qv = make_float4(Ov.x*inva, Ov.y*inva, Ov.z*inva, Ov.w*inva);
        outq[(size_t)(row0g + r) * 128 + q] = qv;
        float4 xv = Xs[r][q];
        float dx;
        dx = qv.x - xv.x; lsum += dx*dx;
        dx = qv.y - xv.y; lsum += dx*dx;
        dx = qv.z - xv.z; lsum += dx*dx;
        dx = qv.w - xv.w; lsum += dx*dx;
    }
    #pragma unroll
    for (int m = 32; m >= 1; m >>= 1) lsum += __shfl_xor(lsum, m);
    if ((tid & 63) == 0) red4[tid >> 6] = lsum;
    __syncthreads();
    if (tid == 0) {
        wloss[blockIdx.x] = red4[0] + red4[1] + red4[2] + red4[3];
        float es = 0.f;
        for (int r = 0; r < BR; ++r) es += ent_s[r];
        went[blockIdx.x] = es;
    }
}

__global__ __launch_bounds__(256) void vq_finalize_fb(const float* __restrict__ wloss,
                                                      const float* __restrict__ went,
                                                      float* __restrict__ out) {
    __shared__ float redl[4], rede[4];
    int tid = threadIdx.x;
    float l = wloss[tid];
    float e = went[tid];
    #pragma unroll
    for (int m = 32; m >= 1; m >>= 1) { l += __shfl_xor(l, m); e += __shfl_xor(e, m); }
    if ((tid & 63) == 0) { redl[tid >> 6] = l; rede[tid >> 6] = e; }
    __syncthreads();
    if (tid == 0) {
        float L = (redl[0] + redl[1] + redl[2] + redl[3]) * (1.0f / 2097152.0f);
        float E = (rede[0] + rede[1] + rede[2] + rede[3]) * (1.0f / 4096.0f);
        out[L0_OFF]  = L;
        out[L1_OFF]  = L;
        out[ENT_OFF] = E;
    }
}

// ================= launcher =================
extern "C" void kernel_launch(void* const* d_in, const int* in_sizes, int n_in,
                              void* d_out, int out_size, void* d_ws, size_t ws_size,
                              hipStream_t stream) {
    const float* x  = (const float*)d_in[0];
    const float* cb = (const float*)d_in[1];
    const float* u1 = (const float*)d_in[2];
    const float* u2 = (const float*)d_in[3];
    float* out = (float*)d_out;

    const size_t NEED = 0xA018000ULL;   // ~168 MB
    if (ws_size >= NEED) {
        char* w = (char*)d_ws;
        float*  S0   = (float*)w;                      // 128MB (P aliases, pitch 16384 u16/row)
        ushort* xhi  = (ushort*)(w + 0x8000000);       // dead after gemm1
        ushort* xlo  = (ushort*)(w + 0x8400000);
        ushort* chi  = (ushort*)(w + 0x8800000);
        ushort* clo  = (ushort*)(w + 0x9000000);
        ushort* cbT  = (ushort*)(w + 0x9800000);
        float*  csq  = (float*)(w + 0xA000000);
        float*  Aarr = (float*)(w + 0xA008000);
        float*  enta = (float*)(w + 0xA00C000);
        float*  wlp  = (float*)(w + 0xA010000);
        int*    fcnt = (int*)(w + 0xA010400);
        int*    frws = (int*)(w + 0xA010800);
        unsigned long long* packed = (unsigned long long*)(w + 0x8000000);

        vq_csq<<<KCODES / 256, 256, 0, stream>>>(cb, csq, fcnt);
        vq_split<<<2048, 256, 0, stream>>>((const float4*)x, xhi, xlo);
        vq_split<<<4096, 256, 0, stream>>>((const float4*)cb, chi, clo);
        vq_trans<<<dim3(128, 8), 256, 0, stream>>>(cb, cbT);
        vq_gemm1<<<dim3(64, 32), 256, 0, stream>>>(xhi, xlo, chi, clo, csq, S0);
        vq_soft<<<NROWS, 1024, 0, stream>>>(S0, u1, u2, Aarr, enta, out, fcnt, frws, packed);
        vq_gemm2b<<<256, 512, 0, stream>>>((const ushort*)S0, cbT, Aarr, x, out, wlp);
        vq_fixup2<<<1024, 256, 0, stream>>>(x, cb, u2, csq, fcnt, frws, packed);
        vq_finalize2<<<1, 256, 0, stream>>>(wlp, enta, fcnt, frws, packed, out);
    } else {
        float* ws  = (float*)d_ws;
        float* csq    = ws;
        float* wlossp = ws + KCODES;
        float* wentp  = ws + KCODES + 256;
        int*   fcnt   = (int*)(ws + KCODES + 512);
        int*   frows  = fcnt + 1;

        vq_csq<<<KCODES / 256, 256, 0, stream>>>(cb, csq, fcnt);
        vq_main_fb<<<NROWS / BR, 256, 0, stream>>>(x, cb, u1, u2, csq, out,
                                                   wlossp, wentp, fcnt, frows);
        vq_fixup<<<256, 256, 0, stream>>>(x, cb, u2, csq, fcnt, frows, out);
        vq_finalize_fb<<<1, 256, 0, stream>>>(wlossp, wentp, out);
    }
}

// Round 9
// 366.653 us; speedup vs baseline: 1.0307x; 1.0307x over previous
//
#include <hip/hip_runtime.h>
#include <math.h>

#define NROWS 4096
#define KCODES 8192
#define DDIM 512
#define IDX_OFF 2097152    // NROWS*DDIM
#define L0_OFF  2101248
#define L1_OFF  2101249
#define ENT_OFF 2101250
#define ARGMAX_MARGIN 0.05f
#define FIX_CHUNK 256
#define FIX_CPR (KCODES / FIX_CHUNK)   // 32 chunks per flagged row

#define TOP2_UPD(v1, k1, v2, k2, h, k)                                 \
    do {                                                               \
        if ((h) > (v1)) { v2 = v1; k2 = k1; v1 = (h); k1 = (k); }      \
        else if ((h) > (v2)) { v2 = (h); k2 = (k); }                   \
    } while (0)

typedef __attribute__((ext_vector_type(8))) short bf16x8;
typedef __attribute__((ext_vector_type(4))) float f32x4;

// fast gumbel: hardware log (v_log_f32), error ~1e-5 absolute -- covered by
// the 0.05 fixup margin and negligible vs bf16 P storage.
__device__ __forceinline__ float gumbelfast(float u) {
    float a = __logf(u + 1e-10f);
    float b = __logf(1e-10f - a);
    return -b;
}
__device__ __forceinline__ ushort f2bf(float f) {
    uint u = __float_as_uint(f);
    return (ushort)((u + 0x7FFFu + ((u >> 16) & 1u)) >> 16);
}
__device__ __forceinline__ float bf2f(ushort h) {
    return __uint_as_float(((uint)h) << 16);
}

// ---- numpy-faithful fp32 helpers ----
__device__ __forceinline__ float np_log32(float x) {
    return (float)log((double)x);
}
__device__ __forceinline__ float np_gumbel(float u) {
    float a  = __fadd_rn(u, 1e-10f);
    float la = np_log32(a);
    float b  = __fadd_rn(-la, 1e-10f);
    float lb = np_log32(b);
    return -lb;
}
__device__ float np_sumsq512(const float* __restrict__ a) {
    float blk[4];
    #pragma unroll
    for (int b = 0; b < 4; ++b) {
        const float* p = a + b * 128;
        float r[8];
        #pragma unroll
        for (int j = 0; j < 8; ++j) r[j] = __fmul_rn(p[j], p[j]);
        for (int i = 8; i < 128; i += 8) {
            #pragma unroll
            for (int j = 0; j < 8; ++j)
                r[j] = __fadd_rn(r[j], __fmul_rn(p[i + j], p[i + j]));
        }
        blk[b] = __fadd_rn(__fadd_rn(__fadd_rn(r[0], r[1]), __fadd_rn(r[2], r[3])),
                           __fadd_rn(__fadd_rn(r[4], r[5]), __fadd_rn(r[6], r[7])));
    }
    return __fadd_rn(__fadd_rn(blk[0], blk[1]), __fadd_rn(blk[2], blk[3]));
}

__device__ __forceinline__ float dot4(float4 a, float4 b) {
    return a.x*b.x + a.y*b.y + a.z*b.z + a.w*b.w;
}
__device__ __forceinline__ void fma4(float4& o, float p, float4 c) {
    o.x += p*c.x; o.y += p*c.y; o.z += p*c.z; o.w += p*c.w;
}

// ================= c_sq: parallel, bit-exact np_sumsq512 =================
// 32 lanes per row: lane (8b+j) runs accumulator r[j] of 128-block b with the
// exact serial chain; shfl_xor 1/2/4 reproduce the balanced fadd tree for the
// group leader; xor 8/16 reproduce the block combine. Lane 0's value is
// bit-identical to np_sumsq512 (each partner's value is exactly the fadd of
// its subtree in the same shape).
__global__ __launch_bounds__(256) void vq_csq2(const float* __restrict__ cb,
                                               float* __restrict__ csq,
                                               int* __restrict__ flag_cnt) {
    if (blockIdx.x == 0 && threadIdx.x == 0) flag_cnt[0] = 0;
    const int tid = threadIdx.x;
    const int row = blockIdx.x * 8 + (tid >> 5);
    const int rl  = tid & 31;          // lane within row-group
    const int b   = rl >> 3, j = rl & 7;
    const float* p = cb + (size_t)row * DDIM + b * 128 + j;
    float r = __fmul_rn(p[0], p[0]);
    #pragma unroll
    for (int i = 1; i < 16; ++i) {
        float v = p[i * 8];
        r = __fadd_rn(r, __fmul_rn(v, v));
    }
    r = __fadd_rn(r, __shfl_xor(r, 1));    // (r0+r1) etc.
    r = __fadd_rn(r, __shfl_xor(r, 2));    // ((r0+r1)+(r2+r3))
    r = __fadd_rn(r, __shfl_xor(r, 4));    // blk[b]
    r = __fadd_rn(r, __shfl_xor(r, 8));    // blk0+blk1
    r = __fadd_rn(r, __shfl_xor(r, 16));   // total
    if (rl == 0) csq[row] = r;
}

// ---------------- R3-proven serial fixup (fallback path only) ----------------
__global__ __launch_bounds__(256) void vq_fixup(
        const float* __restrict__ x, const float* __restrict__ cb,
        const float* __restrict__ u2, const float* __restrict__ csq,
        const int* __restrict__ flag_cnt, const int* __restrict__ flag_rows,
        float* __restrict__ out) {
    __shared__ float xrow[DDIM];
    __shared__ float bv[4];
    __shared__ int   bk[4];
    const int n = flag_cnt[0];
    for (int w = blockIdx.x; w < n; w += gridDim.x) {
        const int row = flag_rows[w];
        for (int i = threadIdx.x; i < DDIM; i += 256)
            xrow[i] = x[(size_t)row * DDIM + i];
        __syncthreads();
        const float xsq = np_sumsq512(xrow);
        float best = -1e30f; int bidx = 0x7fffffff;
        for (int k = threadIdx.x; k < KCODES; k += 256) {
            const float* c = cb + (size_t)k * DDIM;
            float acc1 = 0.f, acc2 = 0.f;
            #pragma unroll 8
            for (int d = 0; d < 384; ++d) acc1 = fmaf(xrow[d], c[d], acc1);
            #pragma unroll 8
            for (int d = 384; d < DDIM; ++d) acc2 = fmaf(xrow[d], c[d], acc2);
            float xc = __fadd_rn(acc1, acc2);
            float t1 = __fadd_rn(xsq, csq[k]);
            float t2 = __fmul_rn(2.0f, xc);
            float t3 = __fsub_rn(t1, t2);
            float logit = -t3;
            float h = __fadd_rn(logit, np_gumbel(u2[(size_t)row * KCODES + k]));
            if (h > best || (h == best && k < bidx)) { best = h; bidx = k; }
        }
        const int lane = threadIdx.x & 63, wv = threadIdx.x >> 6;
        #pragma unroll
        for (int m = 32; m >= 1; m >>= 1) {
            float ov = __shfl_xor(best, m); int ok = __shfl_xor(bidx, m);
            if (ov > best || (ov == best && ok < bidx)) { best = ov; bidx = ok; }
        }
        if (lane == 0) { bv[wv] = best; bk[wv] = bidx; }
        __syncthreads();
        if (threadIdx.x == 0) {
            float b = bv[0]; int bi = bk[0];
            #pragma unroll
            for (int i = 1; i < 4; ++i)
                if (bv[i] > b || (bv[i] == b && bk[i] < bi)) { b = bv[i]; bi = bk[i]; }
            out[IDX_OFF + row] = (float)bi;
        }
        __syncthreads();
    }
}

// ---------------- parallel fixup: (row x chunk) work items, packed atomicMax ----------------
__global__ __launch_bounds__(256) void vq_fixup2(
        const float* __restrict__ x, const float* __restrict__ cb,
        const float* __restrict__ u2, const float* __restrict__ csq,
        const int* __restrict__ flag_cnt, const int* __restrict__ flag_rows,
        unsigned long long* __restrict__ packed) {
    __shared__ float xrow[DDIM];
    __shared__ float xsq_sh;
    __shared__ unsigned long long redp[4];
    const int n = flag_cnt[0];
    const int total = n * FIX_CPR;
    for (int item = blockIdx.x; item < total; item += gridDim.x) {
        const int w = item / FIX_CPR;
        const int chunk = item - w * FIX_CPR;
        const int row = flag_rows[w];
        __syncthreads();                       // protect xrow across loop iters
        for (int i = threadIdx.x; i < DDIM; i += 256)
            xrow[i] = x[(size_t)row * DDIM + i];
        __syncthreads();
        if (threadIdx.x == 0) xsq_sh = np_sumsq512(xrow);
        __syncthreads();
        const float xsq = xsq_sh;
        const int k = chunk * FIX_CHUNK + threadIdx.x;
        const float* c = cb + (size_t)k * DDIM;
        float acc1 = 0.f, acc2 = 0.f;
        #pragma unroll 8
        for (int d = 0; d < 384; ++d) acc1 = fmaf(xrow[d], c[d], acc1);
        #pragma unroll 8
        for (int d = 384; d < DDIM; ++d) acc2 = fmaf(xrow[d], c[d], acc2);
        float xc = __fadd_rn(acc1, acc2);
        float t1 = __fadd_rn(xsq, csq[k]);
        float t2 = __fmul_rn(2.0f, xc);
        float logit = -__fsub_rn(t1, t2);
        float h = __fadd_rn(logit, np_gumbel(u2[(size_t)row * KCODES + k]));
        uint hb = __float_as_uint(h);
        uint key = (hb & 0x80000000u) ? ~hb : (hb | 0x80000000u);
        unsigned long long val = ((unsigned long long)key << 32)
                               | (unsigned long long)(0xFFFFFFFFu - (uint)k);
        #pragma unroll
        for (int m = 32; m >= 1; m >>= 1) {
            unsigned long long o = __shfl_xor(val, m);
            if (o > val) val = o;
        }
        if ((threadIdx.x & 63) == 0) redp[threadIdx.x >> 6] = val;
        __syncthreads();
        if (threadIdx.x == 0) {
            unsigned long long v = redp[0];
            if (redp[1] > v) v = redp[1];
            if (redp[2] > v) v = redp[2];
            if (redp[3] > v) v = redp[3];
            atomicMax(&packed[row], v);
        }
    }
}

// ================= FAST PATH =================

// split fp32 -> bf16 hi/lo (x only; cb handled by vq_prep_cb)
__global__ __launch_bounds__(256) void vq_split(const float4* __restrict__ in,
                                                ushort* __restrict__ hi,
                                                ushort* __restrict__ lo) {
    int i = blockIdx.x * 256 + threadIdx.x;
    float4 v = in[i];
    ushort4 h, l;
    h.x = f2bf(v.x); h.y = f2bf(v.y); h.z = f2bf(v.z); h.w = f2bf(v.w);
    l.x = f2bf(v.x - bf2f(h.x)); l.y = f2bf(v.y - bf2f(h.y));
    l.z = f2bf(v.z - bf2f(h.z)); l.w = f2bf(v.w - bf2f(h.w));
    ((ushort4*)hi)[i] = h;
    ((ushort4*)lo)[i] = l;
}

// fused cb prep: chi/clo (hi/lo split) + cbT (transposed hi), one 16MB pass
__global__ __launch_bounds__(256) void vq_prep_cb(const float* __restrict__ cb,
                                                  ushort* __restrict__ chi,
                                                  ushort* __restrict__ clo,
                                                  ushort* __restrict__ cbT) {
    __shared__ ushort T[64][65];
    const int k0 = blockIdx.x * 64, d0 = blockIdx.y * 64;
    const int lane = threadIdx.x & 63, w = threadIdx.x >> 6;
    #pragma unroll
    for (int i = 0; i < 16; ++i) {
        int ky = i * 4 + w;
        size_t g = (size_t)(k0 + ky) * DDIM + d0 + lane;
        float f = cb[g];
        ushort h = f2bf(f);
        chi[g] = h;
        clo[g] = f2bf(f - bf2f(h));
        T[lane][ky] = h;
    }
    __syncthreads();
    #pragma unroll
    for (int i = 0; i < 16; ++i) {
        int dy = i * 4 + w;
        cbT[(size_t)(d0 + dy) * KCODES + k0 + lane] = T[dy][lane];
    }
}

// GEMM1: S0[m][n] = 2*(x.cb^T) - csq[n], split-bf16 3-product MFMA.
// Reg-staged issue-early loads (gemm2b scheme): LOAD(t+1) before MFMA(t),
// ds_write after barrier. Single LDS buffer, global latency hidden by MFMA.
__global__ __launch_bounds__(256) void vq_gemm1(
        const ushort* __restrict__ xhi, const ushort* __restrict__ xlo,
        const ushort* __restrict__ chi, const ushort* __restrict__ clo,
        const float* __restrict__ csq, float* __restrict__ S0) {
    __shared__ short As[2][128 * 72];
    __shared__ short Bs[2][128 * 72];
    const int tid = threadIdx.x;
    const int lane = tid & 63, wid = tid >> 6;
    const int wr = wid >> 1, wc = wid & 1;
    const int m0 = blockIdx.y * 128, n0 = blockIdx.x * 128;

    bf16x8 sAh[4], sAl[4], sBh[4], sBl[4];   // staged next-tile regs
    f32x4 acc[4][4] = {};

    #define G1_LOAD(kkv)                                                       \
        do {                                                                   \
            const int k0_ = (kkv) * 64;                                        \
            _Pragma("unroll")                                                  \
            for (int i = 0; i < 4; ++i) {                                      \
                int c = tid + i * 256;                                         \
                int row = c >> 3, off = (c & 7) * 8;                           \
                size_t gA = (size_t)(m0 + row) * DDIM + k0_ + off;             \
                size_t gB = (size_t)(n0 + row) * DDIM + k0_ + off;             \
                sAh[i] = *(const bf16x8*)(xhi + gA);                           \
                sAl[i] = *(const bf16x8*)(xlo + gA);                           \
                sBh[i] = *(const bf16x8*)(chi + gB);                           \
                sBl[i] = *(const bf16x8*)(clo + gB);                           \
            }                                                                  \
        } while (0)

    #define G1_WRITE()                                                         \
        do {                                                                   \
            _Pragma("unroll")                                                  \
            for (int i = 0; i < 4; ++i) {                                      \
                int c = tid + i * 256;                                         \
                int row = c >> 3, off = (c & 7) * 8;                           \
                int lidx = row * 72 + off;                                     \
                *(bf16x8*)&As[0][lidx] = sAh[i];                               \
                *(bf16x8*)&As[1][lidx] = sAl[i];                               \
                *(bf16x8*)&Bs[0][lidx] = sBh[i];                               \
                *(bf16x8*)&Bs[1][lidx] = sBl[i];                               \
            }                                                                  \
        } while (0)

    G1_LOAD(0);
    G1_WRITE();
    __syncthreads();
    for (int kk = 0; kk < 8; ++kk) {
        if (kk < 7) G1_LOAD(kk + 1);   // issue early; hides under MFMA
        #pragma unroll
        for (int ks = 0; ks < 2; ++ks) {
            const int ko = ks * 32 + (lane >> 4) * 8;
            bf16x8 ah[4], al[4], bh[4], bl[4];
            #pragma unroll
            for (int m = 0; m < 4; ++m) {
                int r = wr * 64 + m * 16 + (lane & 15);
                ah[m] = *(bf16x8*)&As[0][r * 72 + ko];
                al[m] = *(bf16x8*)&As[1][r * 72 + ko];
            }
            #pragma unroll
            for (int n = 0; n < 4; ++n) {
                int r = wc * 64 + n * 16 + (lane & 15);
                bh[n] = *(bf16x8*)&Bs[0][r * 72 + ko];
                bl[n] = *(bf16x8*)&Bs[1][r * 72 + ko];
            }
            #pragma unroll
            for (int m = 0; m < 4; ++m)
                #pragma unroll
                for (int n = 0; n < 4; ++n) {
                    acc[m][n] = __builtin_amdgcn_mfma_f32_16x16x32_bf16(ah[m], bh[n], acc[m][n], 0, 0, 0);
                    acc[m][n] = __builtin_amdgcn_mfma_f32_16x16x32_bf16(ah[m], bl[n], acc[m][n], 0, 0, 0);
                    acc[m][n] = __builtin_amdgcn_mfma_f32_16x16x32_bf16(al[m], bh[n], acc[m][n], 0, 0, 0);
                }
        }
        if (kk < 7) {
            __syncthreads();   // all reads of LDS done
            G1_WRITE();
            __syncthreads();   // writes visible
        }
    }
    #undef G1_LOAD
    #undef G1_WRITE

    #pragma unroll
    for (int n = 0; n < 4; ++n) {
        int col = n0 + wc * 64 + n * 16 + (lane & 15);
        float cq = csq[col];
        #pragma unroll
        for (int m = 0; m < 4; ++m) {
            int rbase = m0 + wr * 64 + m * 16 + ((lane >> 4) << 2);
            #pragma unroll
            for (int j = 0; j < 4; ++j)
                S0[(size_t)(rbase + j) * KCODES + col] = 2.0f * acc[m][n][j] - cq;
        }
    }
}

// row softmax / gumbel / argmax v3: 1024-thread blocks (16 waves), all 6
// float4 loads issued up-front per thread (MLP=6), 8 elements/thread.
// Writes P (bf16) in-place over S0 rows.
__global__ __launch_bounds__(1024) void vq_soft(
        float* __restrict__ S0, const float* __restrict__ u1,
        const float* __restrict__ u2,
        float* __restrict__ Aarr, float* __restrict__ entarr,
        float* __restrict__ out, int* __restrict__ flag_cnt,
        int* __restrict__ flag_rows, unsigned long long* __restrict__ packed) {
    __shared__ float redm[16], redA[16], redB[16];
    __shared__ float rv1[16], rv2[16];
    __shared__ int   rk1[16], rk2[16];
    const int row = blockIdx.x, tid = threadIdx.x;
    const int lane = tid & 63, wid = tid >> 6;
    const size_t base = (size_t)row * KCODES;
    if (tid == 0) packed[row] = 0ULL;

    const int ka = tid * 4;            // 0..4092
    const int kb = 4096 + tid * 4;     // 4096..8188
    // issue all 6 loads before any dependent compute
    float4 Sa = *(const float4*)(S0 + base + ka);
    float4 Sb = *(const float4*)(S0 + base + kb);
    float4 Ua = *(const float4*)(u1 + base + ka);
    float4 Ub = *(const float4*)(u1 + base + kb);
    float4 Va = *(const float4*)(u2 + base + ka);
    float4 Vb = *(const float4*)(u2 + base + kb);

    // argmax candidates (h = S + g(u2))
    float v1 = -1e30f, v2 = -1e30f; int k1 = 0x7fffffff, k2 = 0x7fffffff;
    float h;
    h = Sa.x + gumbelfast(Va.x); TOP2_UPD(v1, k1, v2, k2, h, ka);
    h = Sa.y + gumbelfast(Va.y); TOP2_UPD(v1, k1, v2, k2, h, ka + 1);
    h = Sa.z + gumbelfast(Va.z); TOP2_UPD(v1, k1, v2, k2, h, ka + 2);
    h = Sa.w + gumbelfast(Va.w); TOP2_UPD(v1, k1, v2, k2, h, ka + 3);
    h = Sb.x + gumbelfast(Vb.x); TOP2_UPD(v1, k1, v2, k2, h, kb);
    h = Sb.y + gumbelfast(Vb.y); TOP2_UPD(v1, k1, v2, k2, h, kb + 1);
    h = Sb.z + gumbelfast(Vb.z); TOP2_UPD(v1, k1, v2, k2, h, kb + 2);
    h = Sb.w + gumbelfast(Vb.w); TOP2_UPD(v1, k1, v2, k2, h, kb + 3);

    // soft scores s = (S + g(u1)) / 2
    float4 sa, sb;
    sa.x = (Sa.x + gumbelfast(Ua.x)) * 0.5f;
    sa.y = (Sa.y + gumbelfast(Ua.y)) * 0.5f;
    sa.z = (Sa.z + gumbelfast(Ua.z)) * 0.5f;
    sa.w = (Sa.w + gumbelfast(Ua.w)) * 0.5f;
    sb.x = (Sb.x + gumbelfast(Ub.x)) * 0.5f;
    sb.y = (Sb.y + gumbelfast(Ub.y)) * 0.5f;
    sb.z = (Sb.z + gumbelfast(Ub.z)) * 0.5f;
    sb.w = (Sb.w + gumbelfast(Ub.w)) * 0.5f;
    float mloc = fmaxf(fmaxf(fmaxf(sa.x, sa.y), fmaxf(sa.z, sa.w)),
                       fmaxf(fmaxf(sb.x, sb.y), fmaxf(sb.z, sb.w)));
    #pragma unroll
    for (int m = 32; m >= 1; m >>= 1) mloc = fmaxf(mloc, __shfl_xor(mloc, m));
    if (lane == 0) redm[wid] = mloc;
    __syncthreads();
    float mrow = redm[0];
    #pragma unroll
    for (int i = 1; i < 16; ++i) mrow = fmaxf(mrow, redm[i]);

    // exp, accumulate, pack P
    float A, Be;
    {
        float d0 = sa.x - mrow, d1 = sa.y - mrow, d2 = sa.z - mrow, d3 = sa.w - mrow;
        float e0 = __expf(d0), e1 = __expf(d1), e2 = __expf(d2), e3 = __expf(d3);
        float d4 = sb.x - mrow, d5 = sb.y - mrow, d6 = sb.z - mrow, d7 = sb.w - mrow;
        float e4 = __expf(d4), e5 = __expf(d5), e6 = __expf(d6), e7 = __expf(d7);
        A  = (((e0 + e1) + e2) + e3) + ((((e4 + e5) + e6) + e7));
        Be = (((e0*d0 + e1*d1) + e2*d2) + e3*d3) + ((((e4*d4 + e5*d5) + e6*d6) + e7*d7));
        ushort* Prow = (ushort*)(S0 + base);
        ushort4 pa, pb;
        pa.x = f2bf(e0); pa.y = f2bf(e1); pa.z = f2bf(e2); pa.w = f2bf(e3);
        pb.x = f2bf(e4); pb.y = f2bf(e5); pb.z = f2bf(e6); pb.w = f2bf(e7);
        *(ushort4*)(Prow + ka) = pa;
        *(ushort4*)(Prow + kb) = pb;
    }
    #pragma unroll
    for (int m = 32; m >= 1; m >>= 1) { A += __shfl_xor(A, m); Be += __shfl_xor(Be, m); }
    #pragma unroll
    for (int m = 32; m >= 1; m >>= 1) {
        float ov1 = __shfl_xor(v1, m); int ok1 = __shfl_xor(k1, m);
        float ov2 = __shfl_xor(v2, m); int ok2 = __shfl_xor(k2, m);
        if (ov1 > v1 || (ov1 == v1 && ok1 < k1)) {
            float nv2; int nk2;
            if (v1 > ov2 || (v1 == ov2 && k1 < ok2)) { nv2 = v1; nk2 = k1; }
            else { nv2 = ov2; nk2 = ok2; }
            v1 = ov1; k1 = ok1; v2 = nv2; k2 = nk2;
        } else if (ov1 > v2 || (ov1 == v2 && ok1 < k2)) { v2 = ov1; k2 = ok1; }
    }
    if (lane == 0) {
        redA[wid] = A; redB[wid] = Be;
        rv1[wid] = v1; rv2[wid] = v2; rk1[wid] = k1; rk2[wid] = k2;
    }
    __syncthreads();
    if (tid == 0) {
        float At = 0.f, Bt = 0.f;
        #pragma unroll
        for (int i = 0; i < 16; ++i) { At += redA[i]; Bt += redB[i]; }
        float V1 = rv1[0], V2 = rv2[0]; int K1 = rk1[0], K2 = rk2[0];
        #pragma unroll
        for (int i = 1; i < 16; ++i) {
            float ov1 = rv1[i], ov2 = rv2[i]; int ok1 = rk1[i], ok2 = rk2[i];
            if (ov1 > V1 || (ov1 == V1 && ok1 < K1)) {
                float nv2; int nk2;
                if (V1 > ov2 || (V1 == ov2 && K1 < ok2)) { nv2 = V1; nk2 = K1; }
                else { nv2 = ov2; nk2 = ok2; }
                V1 = ov1; K1 = ok1; V2 = nv2; K2 = nk2;
            } else if (ov1 > V2 || (ov1 == V2 && ok1 < K2)) { V2 = ov1; K2 = ok1; }
        }
        Aarr[row] = At;
        entarr[row] = logf(At) - Bt / At;
        out[IDX_OFF + row] = (float)K1;
        if (V1 - V2 < ARGMAX_MARGIN) {
            int s = atomicAdd(flag_cnt, 1);
            flag_rows[s] = row;
        }
    }
}

// GEMM2 v2: 512 threads, 8 waves (4 row x 2 col), BK=128, reg-staged double
// buffer, XCD-friendly flat grid.
#define G2_BK 128
__global__ __launch_bounds__(512) void vq_gemm2b(
        const ushort* __restrict__ P, const ushort* __restrict__ cbT,
        const float* __restrict__ Aarr, const float* __restrict__ x,
        float* __restrict__ out, float* __restrict__ wloss) {
    __shared__ short Ap[2][128 * 136];
    __shared__ short Bt[2][64 * 136];
    __shared__ float redl[8];
    const int tid = threadIdx.x;
    const int lane = tid & 63, wid = tid >> 6;
    const int wr = wid & 3, wc = wid >> 2;
    const int bid = blockIdx.x;
    const int mblk = bid & 31, nblk = bid >> 5;
    const int m0 = mblk * 128, n0 = nblk * 64;

    bf16x8 rp[4], rb[2];
    f32x4 acc[2][2] = {};

    #define G2_LOAD(t)                                                         \
        do {                                                                   \
            const int k0_ = (t) * G2_BK;                                       \
            _Pragma("unroll")                                                  \
            for (int i = 0; i < 4; ++i) {                                      \
                int c = tid + i * 512;                                         \
                int row = c >> 4, off = (c & 15) * 8;                          \
                rp[i] = *(const bf16x8*)(P + (size_t)(m0 + row) * 16384 + k0_ + off); \
            }                                                                  \
            _Pragma("unroll")                                                  \
            for (int i = 0; i < 2; ++i) {                                      \
                int c = tid + i * 512;                                         \
                int row = c >> 4, off = (c & 15) * 8;                          \
                rb[i] = *(const bf16x8*)(cbT + (size_t)(n0 + row) * 8192 + k0_ + off); \
            }                                                                  \
        } while (0)

    #define G2_WRITE(buf)                                                      \
        do {                                                                   \
            _Pragma("unroll")                                                  \
            for (int i = 0; i < 4; ++i) {                                      \
                int c = tid + i * 512;                                         \
                int row = c >> 4, off = (c & 15) * 8;                          \
                *(bf16x8*)&Ap[buf][row * 136 + off] = rp[i];                   \
            }                                                                  \
            _Pragma("unroll")                                                  \
            for (int i = 0; i < 2; ++i) {                                      \
                int c = tid + i * 512;                                         \
                int row = c >> 4, off = (c & 15) * 8;                          \
                *(bf16x8*)&Bt[buf][row * 136 + off] = rb[i];                   \
            }                                                                  \
        } while (0)

    G2_LOAD(0);
    G2_WRITE(0);
    __syncthreads();
    int cur = 0;
    for (int t = 0; t < KCODES / G2_BK; ++t) {
        if (t < KCODES / G2_BK - 1) G2_LOAD(t + 1);
        #pragma unroll
        for (int ks = 0; ks < 4; ++ks) {
            const int ko = ks * 32 + (lane >> 4) * 8;
            bf16x8 af[2], bfr[2];
            #pragma unroll
            for (int m = 0; m < 2; ++m)
                af[m] = *(bf16x8*)&Ap[cur][(wr * 32 + m * 16 + (lane & 15)) * 136 + ko];
            #pragma unroll
            for (int n = 0; n < 2; ++n)
                bfr[n] = *(bf16x8*)&Bt[cur][(wc * 32 + n * 16 + (lane & 15)) * 136 + ko];
            #pragma unroll
            for (int m = 0; m < 2; ++m)
                #pragma unroll
                for (int n = 0; n < 2; ++n)
                    acc[m][n] = __builtin_amdgcn_mfma_f32_16x16x32_bf16(af[m], bfr[n], acc[m][n], 0, 0, 0);
        }
        if (t < KCODES / G2_BK - 1) {
            __syncthreads();
            G2_WRITE(cur ^ 1);
            __syncthreads();
            cur ^= 1;
        }
    }
    #undef G2_LOAD
    #undef G2_WRITE

    float lsum = 0.f;
    #pragma unroll
    for (int n = 0; n < 2; ++n) {
        int col = n0 + wc * 32 + n * 16 + (lane & 15);
        #pragma unroll
        for (int m = 0; m < 2; ++m) {
            int rbase = m0 + wr * 32 + m * 16 + ((lane >> 4) << 2);
            #pragma unroll
            for (int j = 0; j < 4; ++j) {
                int row = rbase + j;
                float inva = 1.0f / Aarr[row];
                float q = acc[m][n][j] * inva;
                out[(size_t)row * DDIM + col] = q;
                float d = q - x[(size_t)row * DDIM + col];
                lsum += d * d;
            }
        }
    }
    #pragma unroll
    for (int m = 32; m >= 1; m >>= 1) lsum += __shfl_xor(lsum, m);
    if (lane == 0) redl[wid] = lsum;
    __syncthreads();
    if (tid == 0) {
        float s = 0.f;
        #pragma unroll
        for (int i = 0; i < 8; ++i) s += redl[i];
        wloss[bid] = s;
    }
}

__global__ __launch_bounds__(256) void vq_finalize2(
        const float* __restrict__ wloss, const float* __restrict__ entarr,
        const int* __restrict__ flag_cnt, const int* __restrict__ flag_rows,
        const unsigned long long* __restrict__ packed, float* __restrict__ out) {
    __shared__ float redl[4], rede[4];
    int tid = threadIdx.x;
    const int n = flag_cnt[0];
    for (int w = tid; w < n; w += 256) {
        int row = flag_rows[w];
        uint lowbits = (uint)(packed[row] & 0xFFFFFFFFULL);
        out[IDX_OFF + row] = (float)(0xFFFFFFFFu - lowbits);
    }
    float l = wloss[tid];
    float e = 0.f;
    #pragma unroll
    for (int i = 0; i < 16; ++i) e += entarr[tid + i * 256];
    #pragma unroll
    for (int m = 32; m >= 1; m >>= 1) { l += __shfl_xor(l, m); e += __shfl_xor(e, m); }
    if ((tid & 63) == 0) { redl[tid >> 6] = l; rede[tid >> 6] = e; }
    __syncthreads();
    if (tid == 0) {
        float L = (((redl[0] + redl[1]) + redl[2]) + redl[3]) * (1.0f / 2097152.0f);
        float E = (((rede[0] + rede[1]) + rede[2]) + rede[3]) * (1.0f / 4096.0f);
        out[L0_OFF]  = L;
        out[L1_OFF]  = L;
        out[ENT_OFF] = E;
    }
}

// ================= FALLBACK PATH (R3-proven fused kernel) =================
#define BR 16
#define KT 128
#define NUM_KT 64
#define NUM_DC 4

__device__ __forceinline__ float gumbelf(float u) {
    return -logf(-logf(u + 1e-10f) + 1e-10f);
}

__global__ __launch_bounds__(256) void vq_main_fb(
        const float* __restrict__ x, const float* __restrict__ cb,
        const float* __restrict__ u1, const float* __restrict__ u2,
        const float* __restrict__ csq, float* __restrict__ out,
        float* __restrict__ wloss, float* __restrict__ went,
        int* __restrict__ flag_cnt, int* __restrict__ flag_rows) {
    __shared__ float4 Xs[BR][129];
    __shared__ float4 Cs[KT * 32];
    __shared__ float4 Ol[BR][128];
    __shared__ float4 Ps[BR][32];
    __shared__ float  xsq_s[BR];
    __shared__ float  f_s[BR];
    __shared__ float  A_s[BR];
    __shared__ float  ent_s[BR];
    __shared__ float  red4[4];

    const int tid = threadIdx.x;
    const int rg  = tid >> 5;
    const int cg  = tid & 31;
    const int r0  = rg * 2;
    const int r1  = r0 + 1;
    const int row0g = blockIdx.x * BR;
    const float4* cb4 = (const float4*)cb;

    {
        const float4* xg = (const float4*)x + (size_t)row0g * 128;
        #pragma unroll
        for (int i = 0; i < 8; ++i) {
            int idx = tid + i * 256;
            int r = idx >> 7, q = idx & 127;
            Xs[r][q] = xg[r * 128 + q];
            Ol[r][q] = make_float4(0.f, 0.f, 0.f, 0.f);
        }
    }
    __syncthreads();
    {
        int r = tid >> 4, part = tid & 15;
        float s = 0.f;
        #pragma unroll
        for (int q = 0; q < 8; ++q) {
            float4 v = Xs[r][part * 8 + q];
            s += v.x*v.x + v.y*v.y + v.z*v.z + v.w*v.w;
        }
        #pragma unroll
        for (int m = 8; m >= 1; m >>= 1) s += __shfl_xor(s, m);
        if (part == 0) xsq_s[r] = s;
    }
    __syncthreads();
    const float xsq0 = xsq_s[r0];
    const float xsq1 = xsq_s[r1];

    float m0 = -1e30f, m1 = -1e30f;
    float A0 = 0.f, A1 = 0.f;
    float B0 = 0.f, B1 = 0.f;
    float hb0 = -1e30f, hb1 = -1e30f;
    float hc0 = -1e30f, hc1 = -1e30f;
    int   kb0 = 0, kb1 = 0, kc0 = 0, kc1 = 0;

    for (int t = 0; t < NUM_KT; ++t) {
        const int ktb = t * KT;
        float a00=0.f,a01=0.f,a02=0.f,a03=0.f,a10=0.f,a11=0.f,a12=0.f,a13=0.f;

        for (int dc = 0; dc < NUM_DC; ++dc) {
            #pragma unroll
            for (int i = 0; i < 16; ++i) {
                int idx = tid + i * 256;
                int k = idx >> 5, q = idx & 31;
                Cs[k * 32 + (q ^ ((k >> 2) & 7))] =
                    cb4[(size_t)(ktb + k) * 128 + dc * 32 + q];
            }
            __syncthreads();
            const int qb = dc * 32;
            const int c4 = cg * 4;
            #pragma unroll 4
            for (int dd = 0; dd < 32; ++dd) {
                float4 xv0 = Xs[r0][qb + dd];
                float4 xv1 = Xs[r1][qb + dd];
                int swq = dd ^ (cg & 7);
                float4 cv0 = Cs[(c4 + 0) * 32 + swq];
                float4 cv1 = Cs[(c4 + 1) * 32 + swq];
                float4 cv2 = Cs[(c4 + 2) * 32 + swq];
                float4 cv3 = Cs[(c4 + 3) * 32 + swq];
                a00 += dot4(xv0, cv0); a01 += dot4(xv0, cv1);
                a02 += dot4(xv0, cv2); a03 += dot4(xv0, cv3);
                a10 += dot4(xv1, cv0); a11 += dot4(xv1, cv1);
                a12 += dot4(xv1, cv2); a13 += dot4(xv1, cv3);
            }
            __syncthreads();
        }
        {
            const int kg0 = ktb + cg * 4;
            size_t ur0 = (size_t)(row0g + r0) * KCODES + kg0;
            size_t ur1 = (size_t)(row0g + r1) * KCODES + kg0;
            float4 u1a = *(const float4*)(u1 + ur0);
            float4 u1b = *(const float4*)(u1 + ur1);
            float4 u2a = *(const float4*)(u2 + ur0);
            float4 u2b = *(const float4*)(u2 + ur1);
            float cs0 = csq[kg0], cs1 = csq[kg0+1], cs2 = csq[kg0+2], cs3 = csq[kg0+3];
            {
                float l0 = 2.f*a00 - xsq0 - cs0;
                float l1 = 2.f*a01 - xsq0 - cs1;
                float l2 = 2.f*a02 - xsq0 - cs2;
                float l3 = 2.f*a03 - xsq0 - cs3;
                float h;
                h = l0 + gumbelf(u2a.x); TOP2_UPD(hb0, kb0, hc0, kc0, h, kg0);
                h = l1 + gumbelf(u2a.y); TOP2_UPD(hb0, kb0, hc0, kc0, h, kg0+1);
                h = l2 + gumbelf(u2a.z); TOP2_UPD(hb0, kb0, hc0, kc0, h, kg0+2);
                h = l3 + gumbelf(u2a.w); TOP2_UPD(hb0, kb0, hc0, kc0, h, kg0+3);
                float s0 = (l0 + gumbelf(u1a.x)) * 0.5f;
                float s1 = (l1 + gumbelf(u1a.y)) * 0.5f;
                float s2 = (l2 + gumbelf(u1a.z)) * 0.5f;
                float s3 = (l3 + gumbelf(u1a.w)) * 0.5f;
                float tmax = fmaxf(fmaxf(s0, s1), fmaxf(s2, s3));
                #pragma unroll
                for (int m = 16; m >= 1; m >>= 1) tmax = fmaxf(tmax, __shfl_xor(tmax, m));
                float mn = fmaxf(m0, tmax);
                float p0 = expf(s0 - mn), p1 = expf(s1 - mn);
                float p2 = expf(s2 - mn), p3 = expf(s3 - mn);
                float tA = p0 + p1 + p2 + p3;
                float tB = p0*(s0-mn) + p1*(s1-mn) + p2*(s2-mn) + p3*(s3-mn);
                #pragma unroll
                for (int m = 16; m >= 1; m >>= 1) { tA += __shfl_xor(tA, m); tB += __shfl_xor(tB, m); }
                float f = expf(m0 - mn);
                B0 = f * (B0 + (m0 - mn) * A0) + tB;
                A0 = f * A0 + tA;
                m0 = mn;
                Ps[r0][cg] = make_float4(p0, p1, p2, p3);
                if (cg == 0) f_s[r0] = f;
            }
            {
                float l0 = 2.f*a10 - xsq1 - cs0;
                float l1 = 2.f*a11 - xsq1 - cs1;
                float l2 = 2.f*a12 - xsq1 - cs2;
                float l3 = 2.f*a13 - xsq1 - cs3;
                float h;
                h = l0 + gumbelf(u2b.x); TOP2_UPD(hb1, kb1, hc1, kc1, h, kg0);
                h = l1 + gumbelf(u2b.y); TOP2_UPD(hb1, kb1, hc1, kc1, h, kg0+1);
                h = l2 + gumbelf(u2b.z); TOP2_UPD(hb1, kb1, hc1, kc1, h, kg0+2);
                h = l3 + gumbelf(u2b.w); TOP2_UPD(hb1, kb1, hc1, kc1, h, kg0+3);
                float s0 = (l0 + gumbelf(u1b.x)) * 0.5f;
                float s1 = (l1 + gumbelf(u1b.y)) * 0.5f;
                float s2 = (l2 + gumbelf(u1b.z)) * 0.5f;
                float s3 = (l3 + gumbelf(u1b.w)) * 0.5f;
                float tmax = fmaxf(fmaxf(s0, s1), fmaxf(s2, s3));
                #pragma unroll
                for (int m = 16; m >= 1; m >>= 1) tmax = fmaxf(tmax, __shfl_xor(tmax, m));
                float mn = fmaxf(m1, tmax);
                float p0 = expf(s0 - mn), p1 = expf(s1 - mn);
                float p2 = expf(s2 - mn), p3 = expf(s3 - mn);
                float tA = p0 + p1 + p2 + p3;
                float tB = p0*(s0-mn) + p1*(s1-mn) + p2*(s2-mn) + p3*(s3-mn);
                #pragma unroll
                for (int m = 16; m >= 1; m >>= 1) { tA += __shfl_xor(tA, m); tB += __shfl_xor(tB, m); }
                float f = expf(m1 - mn);
                B1 = f * (B1 + (m1 - mn) * A1) + tB;
                A1 = f * A1 + tA;
                m1 = mn;
                Ps[r1][cg] = make_float4(p0, p1, p2, p3);
                if (cg == 0) f_s[r1] = f;
            }
        }
        __syncthreads();

        for (int dc = 0; dc < NUM_DC; ++dc) {
            #pragma unroll
            for (int i = 0; i < 16; ++i) {
                int idx = tid + i * 256;
                int k = idx >> 5, q = idx & 31;
                Cs[k * 32 + (q ^ ((k >> 2) & 7))] =
                    cb4[(size_t)(ktb + k) * 128 + dc * 32 + q];
            }
            __syncthreads();
            float4 o0 = make_float4(0.f,0.f,0.f,0.f);
            float4 o1 = make_float4(0.f,0.f,0.f,0.f);
            #pragma unroll 2
            for (int k4 = 0; k4 < 32; ++k4) {
                float4 pv0 = Ps[r0][k4];
                float4 pv1 = Ps[r1][k4];
                int sq = cg ^ (k4 & 7);
                float4 cva = Cs[(k4*4 + 0) * 32 + sq];
                float4 cvb = Cs[(k4*4 + 1) * 32 + sq];
                float4 cvc = Cs[(k4*4 + 2) * 32 + sq];
                float4 cvd = Cs[(k4*4 + 3) * 32 + sq];
                fma4(o0, pv0.x, cva); fma4(o0, pv0.y, cvb);
                fma4(o0, pv0.z, cvc); fma4(o0, pv0.w, cvd);
                fma4(o1, pv1.x, cva); fma4(o1, pv1.y, cvb);
                fma4(o1, pv1.z, cvc); fma4(o1, pv1.w, cvd);
            }
            float fr0 = f_s[r0], fr1 = f_s[r1];
            int oq = dc * 32 + cg;
            float4 Ov0 = Ol[r0][oq];
            Ov0.x = Ov0.x*fr0 + o0.x; Ov0.y = Ov0.y*fr0 + o0.y;
            Ov0.z = Ov0.z*fr0 + o0.z; Ov0.w = Ov0.w*fr0 + o0.w;
            Ol[r0][oq] = Ov0;
            float4 Ov1 = Ol[r1][oq];
            Ov1.x = Ov1.x*fr1 + o1.x; Ov1.y = Ov1.y*fr1 + o1.y;
            Ov1.z = Ov1.z*fr1 + o1.z; Ov1.w = Ov1.w*fr1 + o1.w;
            Ol[r1][oq] = Ov1;
            __syncthreads();
        }
    }
    {
        float ent0 = logf(A0) - B0 / A0;
        float v1 = hb0, v2 = hc0; int k1 = kb0, k2 = kc0;
        #pragma unroll
        for (int m = 16; m >= 1; m >>= 1) {
            float ov1 = __shfl_xor(v1, m); int ok1 = __shfl_xor(k1, m);
            float ov2 = __shfl_xor(v2, m); int ok2 = __shfl_xor(k2, m);
            if (ov1 > v1 || (ov1 == v1 && ok1 < k1)) {
                float nv2; int nk2;
                if (v1 > ov2 || (v1 == ov2 && k1 < ok2)) { nv2 = v1; nk2 = k1; }
                else { nv2 = ov2; nk2 = ok2; }
                v1 = ov1; k1 = ok1; v2 = nv2; k2 = nk2;
            } else if (ov1 > v2 || (ov1 == v2 && ok1 < k2)) {
                v2 = ov1; k2 = ok1;
            }
        }
        if (cg == 0) {
            out[IDX_OFF + row0g + r0] = (float)k1;
            if (v1 - v2 < ARGMAX_MARGIN) {
                int s = atomicAdd(flag_cnt, 1);
                flag_rows[s] = row0g + r0;
            }
            ent_s[r0] = ent0;
            A_s[r0] = A0;
        }
        float ent1 = logf(A1) - B1 / A1;
        v1 = hb1; v2 = hc1; k1 = kb1; k2 = kc1;
        #pragma unroll
        for (int m = 16; m >= 1; m >>= 1) {
            float ov1 = __shfl_xor(v1, m); int ok1 = __shfl_xor(k1, m);
            float ov2 = __shfl_xor(v2, m); int ok2 = __shfl_xor(k2, m);
            if (ov1 > v1 || (ov1 == v1 && ok1 < k1)) {
                float nv2; int nk2;
                if (v1 > ov2 || (v1 == ov2 && k1 < ok2)) { nv2 = v1; nk2 = k1; }
                else { nv2 = ov2; nk2 = ok2; }
                v1 = ov1; k1 = ok1; v2 = nv2; k2 = nk2;
            } else if (ov1 > v2 || (ov1 == v2 && ok1 < k2)) {
                v2 = ov1; k2 = ok1;
            }
        }
        if (cg == 0) {
            out[IDX_OFF + row0g + r1] = (float)k1;
            if (v1 - v2 < ARGMAX_MARGIN) {
                int s = atomicAdd(flag_cnt, 1);
                flag_rows[s] = row0g + r1;
            }
            ent_s[r1] = ent1;
            A_s[r1] = A1;
        }
    }
    __syncthreads();

    float lsum = 0.f;
    float4* outq = (float4*)out;
    #pragma unroll
    for (int i = 0; i < 8; ++i) {
        int idx = tid + i * 256;
        int r = idx >> 7, q = idx & 127;
        float inva = 1.f / A_s[r];
        float4 Ov = Ol[r][q];
        float4 qv = make_float4(Ov.x*inva, Ov.y*inva, Ov.z*inva, Ov.w*inva);
        outq[(size_t)(row0g + r) * 128 + q] = qv;
        float4 xv = Xs[r][q];
        float dx;
        dx = qv.x - xv.x; lsum += dx*dx;
        dx = qv.y - xv.y; lsum += dx*dx;
        dx = qv.z - xv.z; lsum += dx*dx;
        dx = qv.w - xv.w; lsum += dx*dx;
    }
    #pragma unroll
    for (int m = 32; m >= 1; m >>= 1) lsum += __shfl_xor(lsum, m);
    if ((tid & 63) == 0) red4[tid >> 6] = lsum;
    __syncthreads();
    if (tid == 0) {
        wloss[blockIdx.x] = red4[0] + red4[1] + red4[2] + red4[3];
        float es = 0.f;
        for (int r = 0; r < BR; ++r) es += ent_s[r];
        went[blockIdx.x] = es;
    }
}

__global__ __launch_bounds__(256) void vq_finalize_fb(const float* __restrict__ wloss,
                                                      const float* __restrict__ went,
                                                      float* __restrict__ out) {
    __shared__ float redl[4], rede[4];
    int tid = threadIdx.x;
    float l = wloss[tid];
    float e = went[tid];
    #pragma unroll
    for (int m = 32; m >= 1; m >>= 1) { l += __shfl_xor(l, m); e += __shfl_xor(e, m); }
    if ((tid & 63) == 0) { redl[tid >> 6] = l; rede[tid >> 6] = e; }
    __syncthreads();
    if (tid == 0) {
        float L = (redl[0] + redl[1] + redl[2] + redl[3]) * (1.0f / 2097152.0f);
        float E = (rede[0] + rede[1] + rede[2] + rede[3]) * (1.0f / 4096.0f);
        out[L0_OFF]  = L;
        out[L1_OFF]  = L;
        out[ENT_OFF] = E;
    }
}

// ================= launcher =================
extern "C" void kernel_launch(void* const* d_in, const int* in_sizes, int n_in,
                              void* d_out, int out_size, void* d_ws, size_t ws_size,
                              hipStream_t stream) {
    const float* x  = (const float*)d_in[0];
    const float* cb = (const float*)d_in[1];
    const float* u1 = (const float*)d_in[2];
    const float* u2 = (const float*)d_in[3];
    float* out = (float*)d_out;

    const size_t NEED = 0xA018000ULL;   // ~168 MB
    if (ws_size >= NEED) {
        char* w = (char*)d_ws;
        float*  S0   = (float*)w;                      // 128MB (P aliases, pitch 16384 u16/row)
        ushort* xhi  = (ushort*)(w + 0x8000000);       // dead after gemm1
        ushort* xlo  = (ushort*)(w + 0x8400000);
        ushort* chi  = (ushort*)(w + 0x8800000);
        ushort* clo  = (ushort*)(w + 0x9000000);
        ushort* cbT  = (ushort*)(w + 0x9800000);
        float*  csq  = (float*)(w + 0xA000000);
        float*  Aarr = (float*)(w + 0xA008000);
        float*  enta = (float*)(w + 0xA00C000);
        float*  wlp  = (float*)(w + 0xA010000);
        int*    fcnt = (int*)(w + 0xA010400);
        int*    frws = (int*)(w + 0xA010800);
        unsigned long long* packed = (unsigned long long*)(w + 0x8000000);

        vq_csq2<<<KCODES / 8, 256, 0, stream>>>(cb, csq, fcnt);
        vq_split<<<2048, 256, 0, stream>>>((const float4*)x, xhi, xlo);
        vq_prep_cb<<<dim3(128, 8), 256, 0, stream>>>(cb, chi, clo, cbT);
        vq_gemm1<<<dim3(64, 32), 256, 0, stream>>>(xhi, xlo, chi, clo, csq, S0);
        vq_soft<<<NROWS, 1024, 0, stream>>>(S0, u1, u2, Aarr, enta, out, fcnt, frws, packed);
        vq_gemm2b<<<256, 512, 0, stream>>>((const ushort*)S0, cbT, Aarr, x, out, wlp);
        vq_fixup2<<<1024, 256, 0, stream>>>(x, cb, u2, csq, fcnt, frws, packed);
        vq_finalize2<<<1, 256, 0, stream>>>(wlp, enta, fcnt, frws, packed, out);
    } else {
        float* ws  = (float*)d_ws;
        float* csq    = ws;
        float* wlossp = ws + KCODES;
        float* wentp  = ws + KCODES + 256;
        int*   fcnt   = (int*)(ws + KCODES + 512);
        int*   frows  = fcnt + 1;

        vq_csq2<<<KCODES / 8, 256, 0, stream>>>(cb, csq, fcnt);
        vq_main_fb<<<NROWS / BR, 256, 0, stream>>>(x, cb, u1, u2, csq, out,
                                                   wlossp, wentp, fcnt, frows);
        vq_fixup<<<256, 256, 0, stream>>>(x, cb, u2, csq, fcnt, frows, out);
        vq_finalize_fb<<<1, 256, 0, stream>>>(wlossp, wentp, out);
    }
}